// Round 1
// 227.577 us; speedup vs baseline: 1.0524x; 1.0524x over previous
//
#include <hip/hip_runtime.h>
#include <math.h>
#include <float.h>

#define BB   512
#define NN   512
#define MM   128
#define CC   1024
#define ADDR 134
#define EPSF 1e-8f

__device__ __forceinline__ float softplus_f(float x) {
    return fmaxf(x, 0.0f) + log1pf(expf(-fabsf(x)));
}

__global__ __launch_bounds__(1024, 8) void ntm_head_kernel(
    const float* __restrict__ co,      // B x C
    const float* __restrict__ prev_w,  // B x N
    const float* __restrict__ mem,     // B x N x M
    const float* __restrict__ W_fc,    // C x ADDR
    const float* __restrict__ b_fc,    // ADDR
    float* __restrict__ out_rv,        // B x M
    float* __restrict__ out_w)         // B x N
{
    __shared__ __align__(16) float s_co[CC];      // 4 KB
    __shared__ __align__(16) float s_k[MM];       // 512 B
    __shared__ float s_extra[8];
    __shared__ __align__(16) float s_bsim[NN];    // 2 KB (reused for pass-2 reduce)
    __shared__ float s_wg[NN];                    // 2 KB
    __shared__ float s_w[NN];                     // 2 KB
    __shared__ __align__(16) float s_part[32 * MM]; // 16 KB (fc partials + pass-2 partials)
    __shared__ float s_red[16];
    __shared__ float s_params[8];

    const int t = threadIdx.x;
    const int b = blockIdx.x;

    // ---- phase 0: stage controller_out row (1 elem/thread) ----
    s_co[t] = co[(size_t)b * CC + t];

    // prefetch prev_w early; consumed much later in the gate step
    float pw = 0.0f;
    if (t < NN) pw = prev_w[(size_t)b * NN + t];

    __syncthreads();

    // ---- phase 1: fc (out = co @ W_fc + b_fc), 8 C-partials x 128 outputs ----
    {
        const int o    = t & (MM - 1);   // output column 0..127
        const int part = t >> 7;         // C-chunk 0..7 (wave-uniform)
        const float* Wp = W_fc + o;
        float a0 = 0.f, a1 = 0.f, a2 = 0.f, a3 = 0.f;
        const int c0 = part * (CC / 8);
        for (int c = c0; c < c0 + CC / 8; c += 4) {
            float4 cv = *(const float4*)(s_co + c);   // LDS broadcast (wave-uniform addr)
            a0 = fmaf(cv.x, Wp[(size_t)(c + 0) * ADDR], a0);
            a1 = fmaf(cv.y, Wp[(size_t)(c + 1) * ADDR], a1);
            a2 = fmaf(cv.z, Wp[(size_t)(c + 2) * ADDR], a2);
            a3 = fmaf(cv.w, Wp[(size_t)(c + 3) * ADDR], a3);
        }
        s_part[part * MM + o] = (a0 + a1) + (a2 + a3);

        // 6 extra columns: one wave each, 16 strided L2-hot loads per lane
        const int wv = t >> 6;
        if (wv < 6) {
            const int l  = t & 63;
            const int oe = MM + wv;
            const float* We = W_fc + oe;
            float e = 0.f;
            for (int c = l; c < CC; c += 64)
                e = fmaf(s_co[c], We[(size_t)c * ADDR], e);
            #pragma unroll
            for (int off = 32; off >= 1; off >>= 1) e += __shfl_xor(e, off, 64);
            if (l == 0) s_extra[wv] = e + b_fc[oe];
        }
    }
    __syncthreads();

    // ---- phase 1b: reduce fc partials, ||k||, scalar params ----
    if (t < MM) {
        float r = b_fc[t];
        #pragma unroll
        for (int p = 0; p < 8; ++p) r += s_part[p * MM + t];
        s_k[t] = r;
        float v = r * r;
        #pragma unroll
        for (int off = 32; off >= 1; off >>= 1) v += __shfl_xor(v, off, 64);
        if ((t & 63) == 0) s_red[t >> 6] = v;
    }
    __syncthreads();
    if (t == 0) {
        float ks = s_red[0] + s_red[1];
        float norm_k = sqrtf(ks) + EPSF;
        float beta = softplus_f(s_extra[0]);
        float g = 1.0f / (1.0f + expf(-s_extra[1]));
        float e0 = s_extra[2], e1 = s_extra[3], e2 = s_extra[4];
        float mx = fmaxf(e0, fmaxf(e1, e2));
        float x0 = expf(e0 - mx), x1 = expf(e1 - mx), x2 = expf(e2 - mx);
        float inv = 1.0f / (x0 + x1 + x2);
        s_params[0] = beta / norm_k;
        s_params[1] = g;
        s_params[2] = x0 * inv;
        s_params[3] = x1 * inv;
        s_params[4] = x2 * inv;
        s_params[5] = 1.0f + softplus_f(s_extra[5]);
    }
    __syncthreads();

    const float bnk = s_params[0];
    const float4* memb = (const float4*)(mem + (size_t)b * NN * MM);
    const int gi = t >> 5;   // 32 groups of 32 lanes
    const int l  = t & 31;

    // ---- pass 1: beta * cosine similarity per row (16 rows/group, 4-row unroll) ----
    {
        float4 kv = ((const float4*)s_k)[l];
        for (int j = 0; j < 16; j += 4) {
            const int r0 = gi + (j    ) * 32;
            const int r1 = gi + (j + 1) * 32;
            const int r2 = gi + (j + 2) * 32;
            const int r3 = gi + (j + 3) * 32;
            float4 a0 = memb[r0 * 32 + l];
            float4 a1 = memb[r1 * 32 + l];
            float4 a2 = memb[r2 * 32 + l];
            float4 a3 = memb[r3 * 32 + l];
            float d0 = a0.x*kv.x + a0.y*kv.y + a0.z*kv.z + a0.w*kv.w;
            float q0 = a0.x*a0.x + a0.y*a0.y + a0.z*a0.z + a0.w*a0.w;
            float d1 = a1.x*kv.x + a1.y*kv.y + a1.z*kv.z + a1.w*kv.w;
            float q1 = a1.x*a1.x + a1.y*a1.y + a1.z*a1.z + a1.w*a1.w;
            float d2 = a2.x*kv.x + a2.y*kv.y + a2.z*kv.z + a2.w*kv.w;
            float q2 = a2.x*a2.x + a2.y*a2.y + a2.z*a2.z + a2.w*a2.w;
            float d3 = a3.x*kv.x + a3.y*kv.y + a3.z*kv.z + a3.w*kv.w;
            float q3 = a3.x*a3.x + a3.y*a3.y + a3.z*a3.z + a3.w*a3.w;
            #pragma unroll
            for (int off = 16; off >= 1; off >>= 1) {
                d0 += __shfl_xor(d0, off, 64); q0 += __shfl_xor(q0, off, 64);
                d1 += __shfl_xor(d1, off, 64); q1 += __shfl_xor(q1, off, 64);
                d2 += __shfl_xor(d2, off, 64); q2 += __shfl_xor(q2, off, 64);
                d3 += __shfl_xor(d3, off, 64); q3 += __shfl_xor(q3, off, 64);
            }
            if (l == 0) {
                s_bsim[r0] = bnk * d0 / (sqrtf(q0) + EPSF);
                s_bsim[r1] = bnk * d1 / (sqrtf(q1) + EPSF);
                s_bsim[r2] = bnk * d2 / (sqrtf(q2) + EPSF);
                s_bsim[r3] = bnk * d3 / (sqrtf(q3) + EPSF);
            }
        }
    }
    __syncthreads();

    // ---- softmax -> gate -> shift -> sharpen -> normalize (1 elem/thread, waves 0-7) ----
    {
        const float NEG = -3.0e38f;
        float b1 = (t < NN) ? s_bsim[t] : NEG;

        float m = b1;
        #pragma unroll
        for (int off = 32; off >= 1; off >>= 1) m = fmaxf(m, __shfl_xor(m, off, 64));
        if ((t & 63) == 0) s_red[t >> 6] = m;
        __syncthreads();
        float M8 = s_red[0];
        #pragma unroll
        for (int i = 1; i < 8; ++i) M8 = fmaxf(M8, s_red[i]);
        __syncthreads();

        float e1 = (t < NN) ? expf(b1 - M8) : 0.0f;
        float ls = e1;
        #pragma unroll
        for (int off = 32; off >= 1; off >>= 1) ls += __shfl_xor(ls, off, 64);
        if ((t & 63) == 0) s_red[t >> 6] = ls;
        __syncthreads();
        float S = s_red[0];
        #pragma unroll
        for (int i = 1; i < 8; ++i) S += s_red[i];
        __syncthreads();

        const float invS = 1.0f / S;
        const float g = s_params[1];
        float wg1 = fmaf(g, e1 * invS, (1.0f - g) * pw);
        if (t < NN) s_wg[t] = wg1;
        __syncthreads();

        const float sh0 = s_params[2], sh1 = s_params[3], sh2 = s_params[4];
        const float gamma = s_params[5];
        float wp1 = 0.0f;
        if (t < NN) {
            float ws1 = sh0 * s_wg[(t + NN - 1) & (NN - 1)]
                      + sh1 * wg1
                      + sh2 * s_wg[(t + 1) & (NN - 1)];
            wp1 = powf(ws1, gamma);
        }
        float lz = wp1;
        #pragma unroll
        for (int off = 32; off >= 1; off >>= 1) lz += __shfl_xor(lz, off, 64);
        if ((t & 63) == 0) s_red[t >> 6] = lz;
        __syncthreads();
        float Z = s_red[0];
        #pragma unroll
        for (int i = 1; i < 8; ++i) Z += s_red[i];
        __syncthreads();

        const float invZ = 1.0f / (Z + EPSF);
        if (t < NN) {
            float w1 = wp1 * invZ;
            s_w[t] = w1;
            out_w[(size_t)b * NN + t] = w1;
        }
    }
    __syncthreads();

    // ---- pass 2: read_vec = w @ mem (16 rows/group, 4-row unroll) ----
    {
        float4 acc = make_float4(0.f, 0.f, 0.f, 0.f);
        for (int j = 0; j < 16; j += 4) {
            const int r0 = gi + (j    ) * 32;
            const int r1 = gi + (j + 1) * 32;
            const int r2 = gi + (j + 2) * 32;
            const int r3 = gi + (j + 3) * 32;
            float4 a0 = memb[r0 * 32 + l];
            float4 a1 = memb[r1 * 32 + l];
            float4 a2 = memb[r2 * 32 + l];
            float4 a3 = memb[r3 * 32 + l];
            float w0 = s_w[r0], w1 = s_w[r1], w2 = s_w[r2], w3 = s_w[r3];
            acc.x = fmaf(w0, a0.x, acc.x); acc.y = fmaf(w0, a0.y, acc.y);
            acc.z = fmaf(w0, a0.z, acc.z); acc.w = fmaf(w0, a0.w, acc.w);
            acc.x = fmaf(w1, a1.x, acc.x); acc.y = fmaf(w1, a1.y, acc.y);
            acc.z = fmaf(w1, a1.z, acc.z); acc.w = fmaf(w1, a1.w, acc.w);
            acc.x = fmaf(w2, a2.x, acc.x); acc.y = fmaf(w2, a2.y, acc.y);
            acc.z = fmaf(w2, a2.z, acc.z); acc.w = fmaf(w2, a2.w, acc.w);
            acc.x = fmaf(w3, a3.x, acc.x); acc.y = fmaf(w3, a3.y, acc.y);
            acc.z = fmaf(w3, a3.z, acc.z); acc.w = fmaf(w3, a3.w, acc.w);
        }
        *((float4*)&s_part[gi * MM + l * 4]) = acc;
        __syncthreads();

        // two-level reduce over 32 group-partials
        if (t < 512) {
            const int h = t >> 7;      // 0..3
            const int o = t & (MM - 1);
            float r = 0.f;
            #pragma unroll
            for (int q = 0; q < 8; ++q) r += s_part[(h * 8 + q) * MM + o];
            s_bsim[h * MM + o] = r;    // s_bsim reused as scratch
        }
        __syncthreads();
        if (t < MM) {
            float r = s_bsim[t] + s_bsim[MM + t] + s_bsim[2 * MM + t] + s_bsim[3 * MM + t];
            out_rv[(size_t)b * MM + t] = r;
        }
    }
}

extern "C" void kernel_launch(void* const* d_in, const int* in_sizes, int n_in,
                              void* d_out, int out_size, void* d_ws, size_t ws_size,
                              hipStream_t stream) {
    const float* co     = (const float*)d_in[0];
    const float* prev_w = (const float*)d_in[1];
    const float* mem    = (const float*)d_in[2];
    const float* W_fc   = (const float*)d_in[3];
    const float* b_fc   = (const float*)d_in[4];
    float* out = (float*)d_out;
    ntm_head_kernel<<<BB, 1024, 0, stream>>>(co, prev_w, mem, W_fc, b_fc,
                                             out, out + (size_t)BB * MM);
}